// Round 1
// baseline (64.433 us; speedup 1.0000x reference)
//
#include <hip/hip_runtime.h>
#include <hip/hip_bf16.h>

constexpr int Bb  = 8;
constexpr int Nn  = 2048;
constexpr int FIN = 128;
constexpr int FOUT = 64;

typedef __bf16 bf16x8 __attribute__((ext_vector_type(8)));
typedef float  f32x4  __attribute__((ext_vector_type(4)));

__device__ __forceinline__ unsigned short f2bf_bits(float f) {
    unsigned int u = __builtin_bit_cast(unsigned int, f);
    return (unsigned short)((u + 0x7FFFu + ((u >> 16) & 1u)) >> 16);  // RNE
}

// Kernel 1: Wh = h@W (fp32 accum) -> bf16 stored in MFMA B-fragment order.
// Also fs = Wh @ a[:64], fd = Wh @ a[64:].
// B-frag layout: frag[b][t32][o16][lane][r] = Wh[t32*32 + (lane>>4)*8 + r][o16*16 + (lane&15)]
__global__ __launch_bounds__(256) void gat_k1(
        const float* __restrict__ h, const float* __restrict__ W,
        const float* __restrict__ a, __bf16* __restrict__ whfrag,
        float* __restrict__ fs, float* __restrict__ fd) {
    const int blk = blockIdx.x;
    const int b   = blk >> 6;          // 64 row-blocks of 32 per batch
    const int t32 = blk & 63;
    const int n0  = t32 * 32;
    const int l   = threadIdx.x & 63;
    const int w   = __builtin_amdgcn_readfirstlane((int)(threadIdx.x >> 6));

    const float a0 = a[l];
    const float a1 = a[FOUT + l];

    float acc[8];
#pragma unroll
    for (int r = 0; r < 8; ++r) acc[r] = 0.f;

    const float* hbase = h + (size_t)(b * Nn + n0 + w * 8) * FIN;

#pragma unroll 1
    for (int c0 = 0; c0 < FIN; c0 += 32) {
        float wreg[32];
#pragma unroll
        for (int cc = 0; cc < 32; ++cc) wreg[cc] = W[(c0 + cc) * FOUT + l];  // coalesced, L2-hot
#pragma unroll
        for (int r = 0; r < 8; ++r) {
            const float* hrow = hbase + r * FIN + c0;   // wave-uniform -> s_load
#pragma unroll
            for (int cc = 0; cc < 32; ++cc) acc[r] = fmaf(hrow[cc], wreg[cc], acc[r]);
        }
    }

    // fs/fd via wave reduction (lane = output channel)
#pragma unroll
    for (int r = 0; r < 8; ++r) {
        float s0 = acc[r] * a0;
        float s1 = acc[r] * a1;
#pragma unroll
        for (int off = 32; off >= 1; off >>= 1) {
            s0 += __shfl_xor(s0, off, 64);
            s1 += __shfl_xor(s1, off, 64);
        }
        if (l == 0) {
            fs[b * Nn + n0 + w * 8 + r] = s0;
            fd[b * Nn + n0 + w * 8 + r] = s1;
        }
    }

    // pack 8 row-values (this lane's o column) into one 16B B-frag slot
    unsigned int pk[4];
#pragma unroll
    for (int i = 0; i < 4; ++i)
        pk[i] = (unsigned int)f2bf_bits(acc[2 * i]) |
                ((unsigned int)f2bf_bits(acc[2 * i + 1]) << 16);
    const int slotg = ((b * 64 + t32) * 4 + (l >> 4)) * 64 + ((w << 4) | (l & 15));
    reinterpret_cast<uint4*>(whfrag)[slotg] = make_uint4(pk[0], pk[1], pk[2], pk[3]);
}

// Kernel 2: fused mask + exp (no max-sub) + PV via MFMA + Z-normalize + ELU.
// Block: 32 rows (i0..i0+31) of batch b, 512 threads = 8 waves.
// Phase A (lanes=j): p for 4 rows/wave -> bf16 -> LDS A-frag (XOR swizzled).
// Phase B: wave (i16=w&1, o16=w>>1) does 2 MFMAs (kb=0,1) per 64-j tile.
__global__ __launch_bounds__(512) void gat_k2(
        const int* __restrict__ adj, const __bf16* __restrict__ whfrag,
        const float* __restrict__ fs, const float* __restrict__ fd,
        float* __restrict__ out) {
    const int blk = blockIdx.x;
    const int b   = blk >> 6;
    const int i0  = (blk & 63) * 32;
    const int l   = threadIdx.x & 63;
    const int w   = __builtin_amdgcn_readfirstlane((int)(threadIdx.x >> 6));

    __shared__ __align__(16) __bf16 afrag[256 * 8];   // 4 KB: [i16][kb][lane][r]
    __shared__ float z_lds[32];

    float fs_loc[4];
#pragma unroll
    for (int rr = 0; rr < 4; ++rr) fs_loc[rr] = fs[b * Nn + i0 + w * 4 + rr];

    float zp[4] = {0.f, 0.f, 0.f, 0.f};
    f32x4 acc = {0.f, 0.f, 0.f, 0.f};

    const int i16 = w & 1;
    const int o16 = w >> 1;

    const int q   = (l >> 3) & 3;   // which 8-k group within the 32-k block
    const int kbw = l >> 5;         // which 32-k block within the 64-j tile
    const int rb  = l & 7;          // element within the 16B frag slot

    const float* fdb  = fd + b * Nn;
    const int*   adjb = adj + (size_t)(b * Nn + i0 + w * 4) * Nn;

    for (int jt = 0; jt < 32; ++jt) {
        const int j0 = jt * 64;
        const float fdj = fdb[j0 + l];
        int av[4];
#pragma unroll
        for (int rr = 0; rr < 4; ++rr)
            av[rr] = adjb[(size_t)rr * Nn + j0 + l];    // coalesced 256B/row

#pragma unroll
        for (int rr = 0; rr < 4; ++rr) {
            const int i_loc = w * 4 + rr;
            float e  = fs_loc[rr] + fdj;
            float lr = fmaxf(e, 0.2f * e);               // leaky relu (slope<1)
            float p  = exp2f(lr * 1.4426950408889634f);  // exp(lr), no max-sub needed
            p = (av[rr] > 0) ? p : 0.f;
            unsigned short pb = f2bf_bits(p);
            zp[rr] += __builtin_bit_cast(float, ((unsigned int)pb) << 16); // Z from rounded p
            int slot = ((i_loc >> 4) * 2 + kbw) * 64 + (i_loc & 15) + (q << 4);
            int elem = ((slot ^ ((slot >> 4) & 7)) << 3) + rb;   // XOR bank swizzle
            afrag[elem] = __builtin_bit_cast(__bf16, pb);
        }
        __syncthreads();

#pragma unroll
        for (int kb = 0; kb < 2; ++kb) {
            int slot  = (i16 * 2 + kb) * 64 + l;
            int rslot = slot ^ ((slot >> 4) & 7);        // same swizzle on read
            bf16x8 avec = *reinterpret_cast<const bf16x8*>(&afrag[rslot << 3]);
            bf16x8 bvec = reinterpret_cast<const bf16x8*>(whfrag)
                              [((b * 64 + jt * 2 + kb) * 4 + o16) * 64 + l];
            acc = __builtin_amdgcn_mfma_f32_16x16x32_bf16(avec, bvec, acc, 0, 0, 0);
        }
        __syncthreads();
    }

    // Z: wave-reduce the per-lane partials for this wave's 4 phase-A rows
#pragma unroll
    for (int rr = 0; rr < 4; ++rr) {
        float z = zp[rr];
#pragma unroll
        for (int off = 32; off >= 1; off >>= 1) z += __shfl_xor(z, off, 64);
        if (l == 0) z_lds[w * 4 + rr] = z;
    }
    __syncthreads();

    // Epilogue: D frag rows = (l>>4)*4 + r, col = l&15 (m89-verified C/D layout)
#pragma unroll
    for (int r = 0; r < 4; ++r) {
        const int i_loc = i16 * 16 + (l >> 4) * 4 + r;
        float v = acc[r] / z_lds[i_loc];
        v = v > 0.f ? v : expm1f(v);                     // ELU
        out[(size_t)(b * Nn + i0 + i_loc) * FOUT + o16 * 16 + (l & 15)] = v;
    }
}

extern "C" void kernel_launch(void* const* d_in, const int* in_sizes, int n_in,
                              void* d_out, int out_size, void* d_ws, size_t ws_size,
                              hipStream_t stream) {
    const float* h   = (const float*)d_in[0];
    const int*   adj = (const int*)d_in[1];
    const float* W   = (const float*)d_in[2];
    const float* a   = (const float*)d_in[3];
    float* out = (float*)d_out;

    __bf16* whfrag = (__bf16*)d_ws;                                   // 2 MB
    float*  fs     = (float*)((char*)d_ws + (size_t)Bb * Nn * FOUT * 2);
    float*  fd     = fs + Bb * Nn;

    gat_k1<<<dim3(Bb * 64), dim3(256), 0, stream>>>(h, W, a, whfrag, fs, fd);
    gat_k2<<<dim3(Bb * 64), dim3(512), 0, stream>>>(adj, whfrag, fs, fd, out);
}

// Round 2
// 57.036 us; speedup vs baseline: 1.1297x; 1.1297x over previous
//
#include <hip/hip_runtime.h>
#include <hip/hip_bf16.h>

constexpr int Bb  = 8;
constexpr int Nn  = 2048;
constexpr int FIN = 128;
constexpr int FOUT = 64;

typedef __bf16 bf16x8 __attribute__((ext_vector_type(8)));
typedef float  f32x4  __attribute__((ext_vector_type(4)));
typedef int    i32x4  __attribute__((ext_vector_type(4)));

__device__ __forceinline__ unsigned int f2bf_bits(float f) {
    unsigned int u = __builtin_bit_cast(unsigned int, f);
    return (u + 0x7FFFu + ((u >> 16) & 1u)) >> 16;  // RNE
}

// Kernel 1: Wh = h@W (fp32 accum) -> bf16 in MFMA B-fragment order.
// B-frag: frag[b][t32][o16][lane][r] = Wh[t32*32 + (lane>>4)*8 + r][o16*16 + (lane&15)]
// Also fs = Wh @ a[:64], fd = Wh @ a[64:].
__global__ __launch_bounds__(256) void gat_k1(
        const float* __restrict__ h, const float* __restrict__ W,
        const float* __restrict__ a, __bf16* __restrict__ whfrag,
        float* __restrict__ fs, float* __restrict__ fd) {
    const int blk = blockIdx.x;
    const int b   = blk >> 6;
    const int t32 = blk & 63;
    const int n0  = t32 * 32;
    const int l   = threadIdx.x & 63;
    const int w   = __builtin_amdgcn_readfirstlane((int)(threadIdx.x >> 6));

    const float a0 = a[l];
    const float a1 = a[FOUT + l];

    float acc[8];
#pragma unroll
    for (int r = 0; r < 8; ++r) acc[r] = 0.f;

    const float* hbase = h + (size_t)(b * Nn + n0 + w * 8) * FIN;

#pragma unroll 1
    for (int c0 = 0; c0 < FIN; c0 += 32) {
        float wreg[32];
#pragma unroll
        for (int cc = 0; cc < 32; ++cc) wreg[cc] = W[(c0 + cc) * FOUT + l];
#pragma unroll
        for (int r = 0; r < 8; ++r) {
            const float* hrow = hbase + r * FIN + c0;   // wave-uniform -> s_load
#pragma unroll
            for (int cc = 0; cc < 32; ++cc) acc[r] = fmaf(hrow[cc], wreg[cc], acc[r]);
        }
    }

#pragma unroll
    for (int r = 0; r < 8; ++r) {
        float s0 = acc[r] * a0;
        float s1 = acc[r] * a1;
#pragma unroll
        for (int off = 32; off >= 1; off >>= 1) {
            s0 += __shfl_xor(s0, off, 64);
            s1 += __shfl_xor(s1, off, 64);
        }
        if (l == 0) {
            fs[b * Nn + n0 + w * 8 + r] = s0;
            fd[b * Nn + n0 + w * 8 + r] = s1;
        }
    }

    unsigned int pk[4];
#pragma unroll
    for (int i = 0; i < 4; ++i)
        pk[i] = f2bf_bits(acc[2 * i]) | (f2bf_bits(acc[2 * i + 1]) << 16);
    const int slotg = ((b * 64 + t32) * 4 + (l >> 4)) * 64 + ((w << 4) | (l & 15));
    reinterpret_cast<uint4*>(whfrag)[slotg] = make_uint4(pk[0], pk[1], pk[2], pk[3]);
}

// Kernel 2: barrier-free main loop. Block = 16 rows, 4 waves = 4 j-quarters.
// Each wave: private LDS A-frag tile (2KB), register double-buffered adj/fd
// prefetch, 8 iter x {16 p-values -> LDS -> 2 ds_read_b128 -> 8 MFMA}.
// One __syncthreads at the end to combine acc and Z partials across waves.
__global__ __launch_bounds__(256, 4) void gat_k2(
        const int* __restrict__ adj, const __bf16* __restrict__ whfrag,
        const float* __restrict__ fs, const float* __restrict__ fd,
        float* __restrict__ out) {
    const int blk = blockIdx.x;              // 1024 blocks
    const int b   = blk >> 7;                // 128 i-tiles per batch
    const int i0  = (blk & 127) * 16;
    const int l   = threadIdx.x & 63;
    const int w   = __builtin_amdgcn_readfirstlane((int)(threadIdx.x >> 6)); // j quarter

    __shared__ __align__(16) char  aLDS[4 * 2048];  // per-wave private A tiles
    __shared__ f32x4 comb[4][4][64];                // 16 KB combine buffer
    __shared__ float zpart[4][16];

    const int g  = l >> 4;      // row group: rows g*4 .. g*4+3
    const int jc = l & 15;      // j sub: j = jc*4 .. jc*4+3 within 64-j tile

    char* myA = aLDS + w * 2048;

    float fs_loc[4];
#pragma unroll
    for (int rr = 0; rr < 4; ++rr) fs_loc[rr] = fs[b * Nn + i0 + g * 4 + rr];

    const int    jq0  = w * 512;
    const float* fdp  = fd + b * Nn + jq0 + jc * 4;
    const int*   adj0 = adj + (size_t)(b * Nn + i0 + g * 4) * Nn + jq0 + jc * 4;

    const bf16x8* bfr = reinterpret_cast<const bf16x8*>(whfrag)
                        + (size_t)((b * 64 + w * 16) * 4) * 64 + l;

    f32x4 acc[4] = {{0,0,0,0},{0,0,0,0},{0,0,0,0},{0,0,0,0}};
    float zp[4]  = {0.f, 0.f, 0.f, 0.f};

    i32x4 adjQ[2][4];
    f32x4 fdQ[2];

#pragma unroll
    for (int rr = 0; rr < 4; ++rr)
        adjQ[0][rr] = *reinterpret_cast<const i32x4*>(adj0 + (size_t)rr * Nn);
    fdQ[0] = *reinterpret_cast<const f32x4*>(fdp);

#pragma unroll
    for (int it = 0; it < 8; ++it) {
        const int cur = it & 1, nxt = cur ^ 1;
        if (it < 7) {  // prefetch next 64-j tile (hides HBM latency under compute)
#pragma unroll
            for (int rr = 0; rr < 4; ++rr)
                adjQ[nxt][rr] = *reinterpret_cast<const i32x4*>(
                                    adj0 + (size_t)rr * Nn + (it + 1) * 64);
            fdQ[nxt] = *reinterpret_cast<const f32x4*>(fdp + (it + 1) * 64);
        }

        // phase A: p = mask ? exp(leakyrelu(fs_i + fd_j)) : 0, bf16, to own LDS
#pragma unroll
        for (int rr = 0; rr < 4; ++rr) {
            const int row = g * 4 + rr;
            unsigned int wds[2];
#pragma unroll
            for (int hp = 0; hp < 2; ++hp) {
                unsigned int wd = 0;
#pragma unroll
                for (int q = 0; q < 2; ++q) {
                    const int jj = hp * 2 + q;
                    float e  = fs_loc[rr] + fdQ[cur][jj];
                    float lr = fmaxf(e, 0.2f * e);                 // leaky relu
                    float p  = exp2f(lr * 1.4426950408889634f);    // exp, no max-sub
                    p = (adjQ[cur][rr][jj] > 0) ? p : 0.f;
                    unsigned int pb = f2bf_bits(p);
                    zp[rr] += __builtin_bit_cast(float, pb << 16); // Z from rounded p
                    wd |= pb << (16 * q);
                }
                wds[hp] = wd;
            }
            const int boff = (row * 128 + jc * 8) ^ ((row & 7) << 4);  // XOR swizzle
            *reinterpret_cast<uint2*>(myA + boff) = make_uint2(wds[0], wds[1]);
        }

        // phase B: A-frags from own LDS (lgkmcnt only, no barrier), 8 MFMA
#pragma unroll
        for (int kb = 0; kb < 2; ++kb) {
            const int rb = ((l & 15) * 128 + kb * 64 + g * 16) ^ ((l & 7) << 4);
            bf16x8 av = *reinterpret_cast<const bf16x8*>(myA + rb);
#pragma unroll
            for (int o16 = 0; o16 < 4; ++o16) {
                bf16x8 bv = bfr[((it * 2 + kb) * 4 + o16) * 64];
                acc[o16] = __builtin_amdgcn_mfma_f32_16x16x32_bf16(av, bv, acc[o16], 0, 0, 0);
            }
        }
    }

    // Z partial: reduce over the 16 lanes of each row group (xor 1,2,4,8)
#pragma unroll
    for (int rr = 0; rr < 4; ++rr) {
#pragma unroll
        for (int off = 1; off <= 8; off <<= 1)
            zp[rr] += __shfl_xor(zp[rr], off, 64);
    }
    if (jc == 0) {
#pragma unroll
        for (int rr = 0; rr < 4; ++rr) zpart[w][g * 4 + rr] = zp[rr];
    }
#pragma unroll
    for (int o16 = 0; o16 < 4; ++o16) comb[w][o16][l] = acc[o16];
    __syncthreads();

    // wave w finalizes output column block o16 = w
    f32x4 res = comb[0][w][l];
#pragma unroll
    for (int wp = 1; wp < 4; ++wp) res += comb[wp][w][l];

#pragma unroll
    for (int r = 0; r < 4; ++r) {
        const int row = g * 4 + r;                     // C/D: row=(l>>4)*4+r, col=l&15
        float z = zpart[0][row] + zpart[1][row] + zpart[2][row] + zpart[3][row];
        float v = res[r] / z;
        v = v > 0.f ? v : expm1f(v);                   // ELU
        out[(size_t)(b * Nn + i0 + row) * FOUT + w * 16 + jc] = v;
    }
}

extern "C" void kernel_launch(void* const* d_in, const int* in_sizes, int n_in,
                              void* d_out, int out_size, void* d_ws, size_t ws_size,
                              hipStream_t stream) {
    const float* h   = (const float*)d_in[0];
    const int*   adj = (const int*)d_in[1];
    const float* W   = (const float*)d_in[2];
    const float* a   = (const float*)d_in[3];
    float* out = (float*)d_out;

    __bf16* whfrag = (__bf16*)d_ws;                                   // 2 MB
    float*  fs     = (float*)((char*)d_ws + (size_t)Bb * Nn * FOUT * 2);
    float*  fd     = fs + Bb * Nn;

    gat_k1<<<dim3(Bb * 64), dim3(256), 0, stream>>>(h, W, a, whfrag, fs, fd);
    gat_k2<<<dim3(Bb * 128), dim3(256), 0, stream>>>(adj, whfrag, fs, fd, out);
}

// Round 4
// 52.515 us; speedup vs baseline: 1.2269x; 1.0861x over previous
//
#include <hip/hip_runtime.h>
#include <hip/hip_bf16.h>

constexpr int Bb  = 8;
constexpr int Nn  = 2048;
constexpr int FIN = 128;
constexpr int FOUT = 64;
constexpr float LOG2E = 1.4426950408889634f;

typedef __bf16 bf16x8 __attribute__((ext_vector_type(8)));
typedef __bf16 bf16x2 __attribute__((ext_vector_type(2)));
typedef float  f32x4  __attribute__((ext_vector_type(4)));
typedef int    i32x4  __attribute__((ext_vector_type(4)));
typedef unsigned int u32;

__device__ __forceinline__ u32 f2bf_bits(float f) {
    u32 u = __builtin_bit_cast(u32, f);
    return (u + 0x7FFFu + ((u >> 16) & 1u)) >> 16;  // RNE
}

// Kernel 1: Wh = h@W (fp32 accum) -> bf16 in MFMA B-fragment order.
// B-frag: frag[b][t32][o16][lane][r] = Wh[t32*32 + (lane>>4)*8 + r][o16*16 + (lane&15)]
// fs = (Wh @ a[:64]) * log2e, fd = (Wh @ a[64:]) * log2e  (pre-scaled for exp2).
__global__ __launch_bounds__(256) void gat_k1(
        const float* __restrict__ h, const float* __restrict__ W,
        const float* __restrict__ a, __bf16* __restrict__ whfrag,
        float* __restrict__ fs, float* __restrict__ fd) {
    const int blk = blockIdx.x;
    const int b   = blk >> 6;
    const int t32 = blk & 63;
    const int n0  = t32 * 32;
    const int l   = threadIdx.x & 63;
    const int w   = __builtin_amdgcn_readfirstlane((int)(threadIdx.x >> 6));

    const float a0 = a[l];
    const float a1 = a[FOUT + l];

    float acc[8];
#pragma unroll
    for (int r = 0; r < 8; ++r) acc[r] = 0.f;

    const float* hbase = h + (size_t)(b * Nn + n0 + w * 8) * FIN;

#pragma unroll 1
    for (int c0 = 0; c0 < FIN; c0 += 32) {
        float wreg[32];
#pragma unroll
        for (int cc = 0; cc < 32; ++cc) wreg[cc] = W[(c0 + cc) * FOUT + l];
#pragma unroll
        for (int r = 0; r < 8; ++r) {
            const float* hrow = hbase + r * FIN + c0;   // wave-uniform -> s_load
#pragma unroll
            for (int cc = 0; cc < 32; ++cc) acc[r] = fmaf(hrow[cc], wreg[cc], acc[r]);
        }
    }

#pragma unroll
    for (int r = 0; r < 8; ++r) {
        float s0 = acc[r] * a0;
        float s1 = acc[r] * a1;
#pragma unroll
        for (int off = 32; off >= 1; off >>= 1) {
            s0 += __shfl_xor(s0, off, 64);
            s1 += __shfl_xor(s1, off, 64);
        }
        if (l == 0) {
            fs[b * Nn + n0 + w * 8 + r] = s0 * LOG2E;
            fd[b * Nn + n0 + w * 8 + r] = s1 * LOG2E;
        }
    }

    u32 pk[4];
#pragma unroll
    for (int i = 0; i < 4; ++i)
        pk[i] = f2bf_bits(acc[2 * i]) | (f2bf_bits(acc[2 * i + 1]) << 16);
    const int slotg = ((b * 64 + t32) * 4 + (l >> 4)) * 64 + ((w << 4) | (l & 15));
    reinterpret_cast<uint4*>(whfrag)[slotg] = make_uint4(pk[0], pk[1], pk[2], pk[3]);
}

// Kernel 2: barrier-free main loop. Block = 16 rows, 4 waves = 4 j-quarters.
// Per-wave A tile is DOUBLE-BUFFERED (2x2KB, parity it&1) and phase A->B is
// fenced with s_waitcnt lgkmcnt(0) + sched_barrier: no LDS RAW/WAR hazard.
__global__ __launch_bounds__(256, 4) void gat_k2(
        const int* __restrict__ adj, const __bf16* __restrict__ whfrag,
        const float* __restrict__ fs, const float* __restrict__ fd,
        float* __restrict__ out) {
    const int blk = blockIdx.x;              // 1024 blocks
    const int b   = blk >> 7;
    const int i0  = (blk & 127) * 16;
    const int l   = threadIdx.x & 63;
    const int w   = __builtin_amdgcn_readfirstlane((int)(threadIdx.x >> 6)); // j quarter

    __shared__ __align__(16) char  aLDS[4 * 4096];  // per-wave 2x2KB double buffer
    __shared__ f32x4 comb[4][4][64];                // 16 KB combine buffer
    __shared__ float zpart[4][16];

    const int g  = l >> 4;      // row group: rows g*4 .. g*4+3
    const int jc = l & 15;      // j sub: j = jc*4 .. jc*4+3 within 64-j tile

    char* myA = aLDS + w * 4096;

    float fs_loc[4];
#pragma unroll
    for (int rr = 0; rr < 4; ++rr) fs_loc[rr] = fs[b * Nn + i0 + g * 4 + rr];

    const int    jq0  = w * 512;
    const float* fdp  = fd + b * Nn + jq0 + jc * 4;
    const int*   adj0 = adj + (size_t)(b * Nn + i0 + g * 4) * Nn + jq0 + jc * 4;

    const bf16x8* bfr = reinterpret_cast<const bf16x8*>(whfrag)
                        + (size_t)((b * 64 + w * 16) * 4) * 64 + l;

    f32x4 acc[4] = {{0,0,0,0},{0,0,0,0},{0,0,0,0},{0,0,0,0}};
    float zp[4]  = {0.f, 0.f, 0.f, 0.f};

    i32x4 adjQ[2][4];
    f32x4 fdQ[2];

#pragma unroll
    for (int rr = 0; rr < 4; ++rr)
        adjQ[0][rr] = *reinterpret_cast<const i32x4*>(adj0 + (size_t)rr * Nn);
    fdQ[0] = *reinterpret_cast<const f32x4*>(fdp);

#pragma unroll 2
    for (int it = 0; it < 8; ++it) {
        const int cur = it & 1, nxt = cur ^ 1;   // compile-time under unroll 2
        if (it < 7) {  // 1-ahead HBM prefetch
#pragma unroll
            for (int rr = 0; rr < 4; ++rr)
                adjQ[nxt][rr] = *reinterpret_cast<const i32x4*>(
                                    adj0 + (size_t)rr * Nn + (it + 1) * 64);
            fdQ[nxt] = *reinterpret_cast<const f32x4*>(fdp + (it + 1) * 64);
        }

        // kb=0 B-frags: issue before phase A so L2 latency hides under VALU
        bf16x8 bv0[4];
#pragma unroll
        for (int o16 = 0; o16 < 4; ++o16)
            bv0[o16] = bfr[((it * 2 + 0) * 4 + o16) * 64];

        // phase A: p = mask ? exp2(max(e',0.2e')) : 0 (fs/fd pre-scaled by log2e)
        char* buf = myA + cur * 2048;
#pragma unroll
        for (int rr = 0; rr < 4; ++rr) {
            const int row = g * 4 + rr;
            u32 wds[2];
#pragma unroll
            for (int hp = 0; hp < 2; ++hp) {
                float pv[2];
#pragma unroll
                for (int q = 0; q < 2; ++q) {
                    const int jj = hp * 2 + q;
                    float e  = fs_loc[rr] + fdQ[cur][jj];
                    float lr = fmaxf(e, 0.2f * e);       // leaky relu (scale-safe)
                    float p  = exp2f(lr);
                    pv[q] = (adjQ[cur][rr][jj] > 0) ? p : 0.f;
                }
                u32 wd = __builtin_bit_cast(u32,
                            (bf16x2){(__bf16)pv[0], (__bf16)pv[1]});
                zp[rr] += __builtin_bit_cast(float, wd << 16);          // lo, rounded
                zp[rr] += __builtin_bit_cast(float, wd & 0xffff0000u);  // hi, rounded
                wds[hp] = wd;
            }
            const int boff = (row * 128 + jc * 8) ^ ((row & 7) << 4);   // XOR swizzle
            *reinterpret_cast<uint2*>(buf + boff) = make_uint2(wds[0], wds[1]);
        }

        // kb=1 B-frags
        bf16x8 bv1[4];
#pragma unroll
        for (int o16 = 0; o16 < 4; ++o16)
            bv1[o16] = bfr[((it * 2 + 1) * 4 + o16) * 64];

        // fence: all this wave's ds_writes committed before the ds_reads below
        asm volatile("s_waitcnt lgkmcnt(0)" ::: "memory");
        __builtin_amdgcn_sched_barrier(0);

        // phase B: 2 ds_read_b128 + 8 MFMA from the current buffer
        {
            const int rb0 = (((l & 15) * 128 + 0 * 64 + g * 16) ^ ((l & 7) << 4));
            bf16x8 av = *reinterpret_cast<const bf16x8*>(buf + rb0);
#pragma unroll
            for (int o16 = 0; o16 < 4; ++o16)
                acc[o16] = __builtin_amdgcn_mfma_f32_16x16x32_bf16(av, bv0[o16], acc[o16], 0, 0, 0);
        }
        {
            const int rb1 = (((l & 15) * 128 + 1 * 64 + g * 16) ^ ((l & 7) << 4));
            bf16x8 av = *reinterpret_cast<const bf16x8*>(buf + rb1);
#pragma unroll
            for (int o16 = 0; o16 < 4; ++o16)
                acc[o16] = __builtin_amdgcn_mfma_f32_16x16x32_bf16(av, bv1[o16], acc[o16], 0, 0, 0);
        }
    }

    // Z partial: reduce over the 16 lanes of each row group
#pragma unroll
    for (int rr = 0; rr < 4; ++rr) {
#pragma unroll
        for (int off = 1; off <= 8; off <<= 1)
            zp[rr] += __shfl_xor(zp[rr], off, 64);
    }
    if (jc == 0) {
#pragma unroll
        for (int rr = 0; rr < 4; ++rr) zpart[w][g * 4 + rr] = zp[rr];
    }
#pragma unroll
    for (int o16 = 0; o16 < 4; ++o16) comb[w][o16][l] = acc[o16];
    __syncthreads();

    // wave w finalizes output column block o16 = w
    f32x4 res = comb[0][w][l];
#pragma unroll
    for (int wp = 1; wp < 4; ++wp) res += comb[wp][w][l];

#pragma unroll
    for (int r = 0; r < 4; ++r) {
        const int row = g * 4 + r;                     // C/D: row=(l>>4)*4+r, col=l&15
        float z = zpart[0][row] + zpart[1][row] + zpart[2][row] + zpart[3][row];
        float v = res[r] / z;
        v = v > 0.f ? v : expm1f(v);                   // ELU
        out[(size_t)(b * Nn + i0 + row) * FOUT + w * 16 + jc] = v;
    }
}

extern "C" void kernel_launch(void* const* d_in, const int* in_sizes, int n_in,
                              void* d_out, int out_size, void* d_ws, size_t ws_size,
                              hipStream_t stream) {
    const float* h   = (const float*)d_in[0];
    const int*   adj = (const int*)d_in[1];
    const float* W   = (const float*)d_in[2];
    const float* a   = (const float*)d_in[3];
    float* out = (float*)d_out;

    __bf16* whfrag = (__bf16*)d_ws;                                   // 2 MB
    float*  fs     = (float*)((char*)d_ws + (size_t)Bb * Nn * FOUT * 2);
    float*  fd     = fs + Bb * Nn;

    gat_k1<<<dim3(Bb * 64), dim3(256), 0, stream>>>(h, W, a, whfrag, fs, fd);
    gat_k2<<<dim3(Bb * 128), dim3(256), 0, stream>>>(adj, whfrag, fs, fd, out);
}

// Round 5
// 49.850 us; speedup vs baseline: 1.2925x; 1.0535x over previous
//
#include <hip/hip_runtime.h>
#include <hip/hip_bf16.h>

constexpr int Bb  = 8;
constexpr int Nn  = 2048;
constexpr int FIN = 128;
constexpr int FOUT = 64;
constexpr float LOG2E = 1.4426950408889634f;

typedef __bf16 bf16x8 __attribute__((ext_vector_type(8)));
typedef __bf16 bf16x2 __attribute__((ext_vector_type(2)));
typedef float  f32x4  __attribute__((ext_vector_type(4)));
typedef int    i32x4  __attribute__((ext_vector_type(4)));
typedef unsigned int u32;

__device__ __forceinline__ u32 f2bf_bits(float f) {
    u32 u = __builtin_bit_cast(u32, f);
    return (u + 0x7FFFu + ((u >> 16) & 1u)) >> 16;  // RNE
}

// Kernel 1: Wh = h@W (fp32 accum) -> bf16 in MFMA B-fragment order.
// B-frag: frag[b][t32][o16][lane][r] = Wh[t32*32 + (lane>>4)*8 + r][o16*16 + (lane&15)]
// fs = (Wh @ a[:64]) * log2e, fd = (Wh @ a[64:]) * log2e  (pre-scaled for exp2).
__global__ __launch_bounds__(256) void gat_k1(
        const float* __restrict__ h, const float* __restrict__ W,
        const float* __restrict__ a, __bf16* __restrict__ whfrag,
        float* __restrict__ fs, float* __restrict__ fd) {
    const int blk = blockIdx.x;
    const int b   = blk >> 6;
    const int t32 = blk & 63;
    const int n0  = t32 * 32;
    const int l   = threadIdx.x & 63;
    const int w   = __builtin_amdgcn_readfirstlane((int)(threadIdx.x >> 6));

    const float a0 = a[l];
    const float a1 = a[FOUT + l];

    float acc[8];
#pragma unroll
    for (int r = 0; r < 8; ++r) acc[r] = 0.f;

    const float* hbase = h + (size_t)(b * Nn + n0 + w * 8) * FIN;

#pragma unroll 1
    for (int c0 = 0; c0 < FIN; c0 += 32) {
        float wreg[32];
#pragma unroll
        for (int cc = 0; cc < 32; ++cc) wreg[cc] = W[(c0 + cc) * FOUT + l];
#pragma unroll
        for (int r = 0; r < 8; ++r) {
            const float* hrow = hbase + r * FIN + c0;   // wave-uniform -> s_load
#pragma unroll
            for (int cc = 0; cc < 32; ++cc) acc[r] = fmaf(hrow[cc], wreg[cc], acc[r]);
        }
    }

#pragma unroll
    for (int r = 0; r < 8; ++r) {
        float s0 = acc[r] * a0;
        float s1 = acc[r] * a1;
#pragma unroll
        for (int off = 32; off >= 1; off >>= 1) {
            s0 += __shfl_xor(s0, off, 64);
            s1 += __shfl_xor(s1, off, 64);
        }
        if (l == 0) {
            fs[b * Nn + n0 + w * 8 + r] = s0 * LOG2E;
            fd[b * Nn + n0 + w * 8 + r] = s1 * LOG2E;
        }
    }

    u32 pk[4];
#pragma unroll
    for (int i = 0; i < 4; ++i)
        pk[i] = f2bf_bits(acc[2 * i]) | (f2bf_bits(acc[2 * i + 1]) << 16);
    const int slotg = ((b * 64 + t32) * 4 + (l >> 4)) * 64 + ((w << 4) | (l & 15));
    reinterpret_cast<uint4*>(whfrag)[slotg] = make_uint4(pk[0], pk[1], pk[2], pk[3]);
}

// Kernel 2: barrier-free main loop. Block = 16 rows, 4 waves = 4 j-quarters.
// Register diet vs r4: no bv prefetch arrays (inline B-frag loads, hoistable
// through sched_barrier(0x20)); Z computed by MFMA row-sum (B = ones) instead
// of per-lane adds. Per-wave A tile double-buffered + lgkmcnt fence.
__global__ __launch_bounds__(256, 4) void gat_k2(
        const int* __restrict__ adj, const __bf16* __restrict__ whfrag,
        const float* __restrict__ fs, const float* __restrict__ fd,
        float* __restrict__ out) {
    const int blk = blockIdx.x;              // 1024 blocks
    const int b   = blk >> 7;
    const int i0  = (blk & 127) * 16;
    const int l   = threadIdx.x & 63;
    const int w   = __builtin_amdgcn_readfirstlane((int)(threadIdx.x >> 6)); // j quarter

    __shared__ __align__(16) char  aLDS[4 * 4096];  // per-wave 2x2KB double buffer
    __shared__ f32x4 comb[4][4][64];                // 16 KB combine buffer
    __shared__ float zpart[4][16];

    const int g  = l >> 4;      // row group: rows g*4 .. g*4+3
    const int jc = l & 15;      // j sub: j = jc*4 .. jc*4+3 within 64-j tile

    char* myA = aLDS + w * 4096;

    float fs_loc[4];
#pragma unroll
    for (int rr = 0; rr < 4; ++rr) fs_loc[rr] = fs[b * Nn + i0 + g * 4 + rr];

    const int    jq0  = w * 512;
    const float* fdp  = fd + b * Nn + jq0 + jc * 4;
    const int*   adj0 = adj + (size_t)(b * Nn + i0 + g * 4) * Nn + jq0 + jc * 4;

    const bf16x8* bfr = reinterpret_cast<const bf16x8*>(whfrag)
                        + (size_t)((b * 64 + w * 16) * 4) * 64 + l;

    f32x4 acc[4] = {{0,0,0,0},{0,0,0,0},{0,0,0,0},{0,0,0,0}};
    f32x4 accz   = {0.f, 0.f, 0.f, 0.f};

    bf16x8 onesv;
#pragma unroll
    for (int i = 0; i < 8; ++i) onesv[i] = (__bf16)1.0f;

    i32x4 adjQ[2][4];
    f32x4 fdQ[2];

#pragma unroll
    for (int rr = 0; rr < 4; ++rr)
        adjQ[0][rr] = *reinterpret_cast<const i32x4*>(adj0 + (size_t)rr * Nn);
    fdQ[0] = *reinterpret_cast<const f32x4*>(fdp);

#pragma unroll 2
    for (int it = 0; it < 8; ++it) {
        const int cur = it & 1, nxt = cur ^ 1;   // compile-time under unroll 2
        if (it < 7) {  // 1-ahead HBM prefetch
#pragma unroll
            for (int rr = 0; rr < 4; ++rr)
                adjQ[nxt][rr] = *reinterpret_cast<const i32x4*>(
                                    adj0 + (size_t)rr * Nn + (it + 1) * 64);
            fdQ[nxt] = *reinterpret_cast<const f32x4*>(fdp + (it + 1) * 64);
        }

        // phase A: p = mask ? exp2(max(e',0.2e')) : 0 (fs/fd pre-scaled by log2e)
        char* buf = myA + cur * 2048;
#pragma unroll
        for (int rr = 0; rr < 4; ++rr) {
            const int row = g * 4 + rr;
            u32 wds[2];
#pragma unroll
            for (int hp = 0; hp < 2; ++hp) {
                float pv[2];
#pragma unroll
                for (int q = 0; q < 2; ++q) {
                    const int jj = hp * 2 + q;
                    float e  = fs_loc[rr] + fdQ[cur][jj];
                    float lr = fmaxf(e, 0.2f * e);       // leaky relu (scale-safe)
                    float p  = exp2f(lr);
                    pv[q] = (adjQ[cur][rr][jj] > 0) ? p : 0.f;
                }
                wds[hp] = __builtin_bit_cast(u32,
                            (bf16x2){(__bf16)pv[0], (__bf16)pv[1]});
            }
            const int boff = (row * 128 + jc * 8) ^ ((row & 7) << 4);   // XOR swizzle
            *reinterpret_cast<uint2*>(buf + boff) = make_uint2(wds[0], wds[1]);
        }

        // fence: this wave's ds_writes committed before phase-B ds_reads.
        // sched_barrier(0x20): only VMEM reads (B-frag loads) may cross.
        asm volatile("s_waitcnt lgkmcnt(0)" ::: "memory");
        __builtin_amdgcn_sched_barrier(0x20);

        // phase B: 2 ds_read_b128 + 10 MFMA (8 PV + 2 Z row-sum)
        {
            const int rb0 = (((l & 15) * 128 + 0 * 64 + g * 16) ^ ((l & 7) << 4));
            bf16x8 av = *reinterpret_cast<const bf16x8*>(buf + rb0);
#pragma unroll
            for (int o16 = 0; o16 < 4; ++o16)
                acc[o16] = __builtin_amdgcn_mfma_f32_16x16x32_bf16(
                               av, bfr[((it * 2 + 0) * 4 + o16) * 64], acc[o16], 0, 0, 0);
            accz = __builtin_amdgcn_mfma_f32_16x16x32_bf16(av, onesv, accz, 0, 0, 0);
        }
        {
            const int rb1 = (((l & 15) * 128 + 1 * 64 + g * 16) ^ ((l & 7) << 4));
            bf16x8 av = *reinterpret_cast<const bf16x8*>(buf + rb1);
#pragma unroll
            for (int o16 = 0; o16 < 4; ++o16)
                acc[o16] = __builtin_amdgcn_mfma_f32_16x16x32_bf16(
                               av, bfr[((it * 2 + 1) * 4 + o16) * 64], acc[o16], 0, 0, 0);
            accz = __builtin_amdgcn_mfma_f32_16x16x32_bf16(av, onesv, accz, 0, 0, 0);
        }
    }

    // Z partials: accz D-frag row=(l>>4)*4+r, col=l&15 (all cols identical)
    if ((l & 15) == 0) {
#pragma unroll
        for (int r = 0; r < 4; ++r) zpart[w][(l >> 4) * 4 + r] = accz[r];
    }
#pragma unroll
    for (int o16 = 0; o16 < 4; ++o16) comb[w][o16][l] = acc[o16];
    __syncthreads();

    // wave w finalizes output column block o16 = w
    f32x4 res = comb[0][w][l];
#pragma unroll
    for (int wp = 1; wp < 4; ++wp) res += comb[wp][w][l];

#pragma unroll
    for (int r = 0; r < 4; ++r) {
        const int row = g * 4 + r;                     // C/D: row=(l>>4)*4+r, col=l&15
        float z = zpart[0][row] + zpart[1][row] + zpart[2][row] + zpart[3][row];
        float v = res[r] / z;
        v = v > 0.f ? v : expm1f(v);                   // ELU
        out[(size_t)(b * Nn + i0 + row) * FOUT + w * 16 + jc] = v;
    }
}

extern "C" void kernel_launch(void* const* d_in, const int* in_sizes, int n_in,
                              void* d_out, int out_size, void* d_ws, size_t ws_size,
                              hipStream_t stream) {
    const float* h   = (const float*)d_in[0];
    const int*   adj = (const int*)d_in[1];
    const float* W   = (const float*)d_in[2];
    const float* a   = (const float*)d_in[3];
    float* out = (float*)d_out;

    __bf16* whfrag = (__bf16*)d_ws;                                   // 2 MB
    float*  fs     = (float*)((char*)d_ws + (size_t)Bb * Nn * FOUT * 2);
    float*  fd     = fs + Bb * Nn;

    gat_k1<<<dim3(Bb * 64), dim3(256), 0, stream>>>(h, W, a, whfrag, fs, fd);
    gat_k2<<<dim3(Bb * 128), dim3(256), 0, stream>>>(adj, whfrag, fs, fd, out);
}